// Round 3
// baseline (2408.677 us; speedup 1.0000x reference)
//
#include <hip/hip_runtime.h>
#include <hip/hip_bf16.h>

#define B_  256
#define T_  256
#define D_  512
#define H_  512
#define G3_ 1536

typedef __attribute__((ext_vector_type(8))) short bf16x8;
typedef __attribute__((ext_vector_type(4))) float f32x4;
typedef __attribute__((ext_vector_type(8))) unsigned short u16x8;
typedef __attribute__((ext_vector_type(4))) unsigned short u16x4;

__device__ inline void gload_lds16(const void* g, void* l) {
  __builtin_amdgcn_global_load_lds((const __attribute__((address_space(1))) void*)g,
                                   (__attribute__((address_space(3))) void*)l,
                                   16, 0, 0);
}

__device__ inline unsigned short f2bu(float f) {
  __hip_bfloat16 h = __float2bfloat16(f);
  return *reinterpret_cast<unsigned short*>(&h);
}
__device__ inline float bu2f(unsigned short u) {
  return __uint_as_float((unsigned)u << 16);
}

// ---- system-coherent (MALL) access helpers: bypass L1/L2 so cross-block
// ---- exchange needs NO cache-maintenance ops per step.
__device__ inline bf16x8 ld16_sys(const void* p) {
  bf16x8 r;
  asm volatile("global_load_dwordx4 %0, %1, off sc0 sc1" : "=v"(r) : "v"(p) : "memory");
  return r;
}
__device__ inline void st8_sys(void* p, u16x4 v) {
  asm volatile("global_store_dwordx2 %0, %1, off sc0 sc1" :: "v"(p), "v"(v) : "memory");
}
__device__ inline void st4_sys(void* p, unsigned v) {
  asm volatile("global_store_dword %0, %1, off sc0 sc1" :: "v"(p), "v"(v) : "memory");
}
__device__ inline unsigned ld4_sys_wait(const void* p) {
  unsigned r;
  asm volatile("global_load_dword %0, %1, off sc0 sc1\n\ts_waitcnt vmcnt(0)"
               : "=v"(r) : "v"(p) : "memory");
  return r;
}
__device__ inline void waitvm0() { asm volatile("s_waitcnt vmcnt(0)" ::: "memory"); }

// ---------------- prep: weights f32->bf16, zero flags ----------------
__global__ void prep_kernel(const float* __restrict__ w_in, const float* __restrict__ w_ih,
                            const float* __restrict__ w_out,
                            __hip_bfloat16* __restrict__ wib, __hip_bfloat16* __restrict__ whb,
                            __hip_bfloat16* __restrict__ wob, unsigned int* __restrict__ ctrs) {
  int i = blockIdx.x * 256 + threadIdx.x;
  if (i < D_ * D_)  wib[i] = __float2bfloat16(w_in[i]);
  if (i < G3_ * D_) whb[i] = __float2bfloat16(w_ih[i]);
  if (i < H_ * H_)  wob[i] = __float2bfloat16(w_out[i]);
  if (i < 1024) ctrs[i] = 0u;
}

// ---------------- LayerNorm + cast to bf16 (1 wave per 512-col row) ----------------
__global__ __launch_bounds__(512) void ln_kernel(const float* __restrict__ x,
                                                 const float* __restrict__ gamma,
                                                 const float* __restrict__ beta,
                                                 __hip_bfloat16* __restrict__ xn) {
  long row = (long)blockIdx.x * 8 + (threadIdx.x >> 6);
  int lane = threadIdx.x & 63;
  const float4* rp = (const float4*)(x + row * D_ + lane * 8);
  float4 v0 = rp[0], v1 = rp[1];
  float s  = v0.x + v0.y + v0.z + v0.w + v1.x + v1.y + v1.z + v1.w;
  float sq = v0.x*v0.x + v0.y*v0.y + v0.z*v0.z + v0.w*v0.w
           + v1.x*v1.x + v1.y*v1.y + v1.z*v1.z + v1.w*v1.w;
  #pragma unroll
  for (int off = 1; off < 64; off <<= 1) { s += __shfl_xor(s, off); sq += __shfl_xor(sq, off); }
  float mean = s * (1.0f / D_);
  float var  = sq * (1.0f / D_) - mean * mean;
  float rstd = rsqrtf(var + 1e-5f);
  const float4* gp = (const float4*)(gamma + lane * 8);
  const float4* bp = (const float4*)(beta + lane * 8);
  float4 g0 = gp[0], g1 = gp[1], bb0 = bp[0], bb1 = bp[1];
  float vv[8] = {v0.x, v0.y, v0.z, v0.w, v1.x, v1.y, v1.z, v1.w};
  float gg[8] = {g0.x, g0.y, g0.z, g0.w, g1.x, g1.y, g1.z, g1.w};
  float bt[8] = {bb0.x, bb0.y, bb0.z, bb0.w, bb1.x, bb1.y, bb1.z, bb1.w};
  u16x8 ov;
  #pragma unroll
  for (int i = 0; i < 8; ++i) ov[i] = f2bu((vv[i] - mean) * rstd * gg[i] + bt[i]);
  *(u16x8*)(xn + row * D_ + lane * 8) = ov;
}

// ---------------- GEMM: C[M,N] = act(A[M,K] @ W[N,K]^T + bias) ----------------
template<int ACT, int OUTBF>
__global__ __launch_bounds__(256) void gemm_bt(const __hip_bfloat16* __restrict__ A,
                                               const __hip_bfloat16* __restrict__ W,
                                               const float* __restrict__ bias,
                                               void* __restrict__ Cout,
                                               int M, int N, int K) {
  __shared__ __hip_bfloat16 As[128 * 64];
  __shared__ __hip_bfloat16 Ws[128 * 64];
  int tid  = threadIdx.x;
  int lane = tid & 63;
  int wave = tid >> 6;
  long row0 = (long)blockIdx.y * 128;
  long col0 = (long)blockIdx.x * 128;
  int qm = (wave >> 1) * 64, qn = (wave & 1) * 64;
  int lr = lane & 15, lk = (lane >> 4) * 8;
  f32x4 acc[4][4];
  #pragma unroll
  for (int mt = 0; mt < 4; ++mt)
    #pragma unroll
    for (int nt = 0; nt < 4; ++nt) acc[mt][nt] = {0.f, 0.f, 0.f, 0.f};

  for (int k0 = 0; k0 < K; k0 += 64) {
    #pragma unroll
    for (int i = 0; i < 4; ++i) {
      int e = i * 2048 + tid * 8;
      int r = e >> 6, c = e & 63;
      gload_lds16(A + (row0 + r) * K + k0 + c, (char*)As + 2 * e);
      gload_lds16(W + (col0 + r) * K + k0 + c, (char*)Ws + 2 * e);
    }
    __syncthreads();
    #pragma unroll
    for (int kc = 0; kc < 2; ++kc) {
      int kb = kc * 32 + lk;
      bf16x8 af[4], wf[4];
      #pragma unroll
      for (int mt = 0; mt < 4; ++mt) af[mt] = *(const bf16x8*)&As[(qm + mt * 16 + lr) * 64 + kb];
      #pragma unroll
      for (int nt = 0; nt < 4; ++nt) wf[nt] = *(const bf16x8*)&Ws[(qn + nt * 16 + lr) * 64 + kb];
      #pragma unroll
      for (int mt = 0; mt < 4; ++mt)
        #pragma unroll
        for (int nt = 0; nt < 4; ++nt)
          acc[mt][nt] = __builtin_amdgcn_mfma_f32_16x16x32_bf16(af[mt], wf[nt], acc[mt][nt], 0, 0, 0);
    }
    __syncthreads();
  }
  int r0 = (lane >> 4) * 4;
  #pragma unroll
  for (int nt = 0; nt < 4; ++nt) {
    long col = col0 + qn + nt * 16 + lr;
    float bv = bias[col];
    #pragma unroll
    for (int mt = 0; mt < 4; ++mt) {
      #pragma unroll
      for (int q = 0; q < 4; ++q) {
        long row = row0 + qm + mt * 16 + r0 + q;
        float v = acc[mt][nt][q] + bv;
        if (ACT) v = fmaxf(v, 0.0f);
        if (OUTBF) ((__hip_bfloat16*)Cout)[row * N + col] = __float2bfloat16(v);
        else       ((float*)Cout)[row * N + col] = v;
      }
    }
  }
}

// ---------------- GRU scan ----------------
// 8 groups (32 batch rows) x 16 blocks (32 h-cols -> 96 w_hh rows LDS-resident).
// MALL-coherent (sc0 sc1) exchange; PER-WAVE flags (wave-autonomous publish:
// no block barrier on the publish or poll path). hs store + gi prefetch for
// t+1 pushed off the critical path (after the flag store).
__global__ __launch_bounds__(256) void scan_kernel(const __hip_bfloat16* __restrict__ gi,
                                                   const float* __restrict__ hidden,
                                                   const int* __restrict__ ep,
                                                   const float* __restrict__ w_hh,
                                                   const float* __restrict__ b_hh,
                                                   __hip_bfloat16* __restrict__ hs,
                                                   __hip_bfloat16* __restrict__ hbuf,
                                                   float* __restrict__ h_last,
                                                   unsigned int* __restrict__ flags) {
  __shared__ __hip_bfloat16 Wl[96][520];   // gate rows: [0,32)=r [32,64)=z [64,96)=n
  __shared__ float ghs[32][100];
  __shared__ unsigned epm[256];            // per-t bitmask of episode starts (32 rows)
  __shared__ float bhhs[96];

  const int tid = threadIdx.x;
  const int bg = blockIdx.x & 7;           // group ~ XCD (heuristic only)
  const int nb = blockIdx.x >> 3;          // 0..15
  const int rb0 = bg * 32;
  const int j0 = nb * 32;
  unsigned* gflags = flags + bg * 64;      // 64 per-wave flags per group

  // W slice f32->bf16 -> LDS (resident all T steps)
  for (int idx = tid; idx < 96 * 512; idx += 256) {
    int row = idx >> 9, c = idx & 511;
    int g = row >> 5, jj = row & 31;
    Wl[row][c] = __float2bfloat16(w_hh[(size_t)(g * 512 + j0 + jj) * 512 + c]);
  }
  if (tid < 96) bhhs[tid] = b_hh[(tid >> 5) * 512 + j0 + (tid & 31)];
  {
    unsigned m = 0;
    for (int b = 0; b < 32; ++b)
      m |= (ep[(rb0 + b) * T_ + tid] != 0) ? (1u << b) : 0u;
    epm[tid] = m;
  }

  const int lane = tid & 63;
  const int wave = tid >> 6;
  const int gb = tid >> 3, gjb = (tid & 7) * 4;   // gate-phase cell (row, 4-col chunk)

  // init h: register master + publish bf16 (buffer 0); per-wave flag = 1
  f32x4 hreg;
  {
    const float4 hv = *(const float4*)(hidden + (size_t)(rb0 + gb) * 512 + j0 + gjb);
    hreg = (f32x4){hv.x, hv.y, hv.z, hv.w};
    u16x4 hb;
    #pragma unroll
    for (int k = 0; k < 4; ++k) hb[k] = f2bu(hreg[k]);
    st8_sys(hbuf + (size_t)(bg * 2) * 32 * 512 + gb * 512 + j0 + gjb, hb);
  }
  waitvm0();
  if (lane == 0) st4_sys(gflags + nb * 4 + wave, 1u);
  __syncthreads();   // Wl / epm / bhhs ready

  const int mt = wave >> 1;                // batch half (rows 0-15 / 16-31)
  const int npair = wave & 1;              // gate half (rows 0-47 / 48-95)
  const int lr = lane & 15;
  const int asub = lane >> 4;
  const int arow = mt * 16 + lr;           // batch row in group

  // loop-invariant gate biases -> registers
  float br_[4], bz_[4], bn_[4];
  #pragma unroll
  for (int k = 0; k < 4; ++k) {
    br_[k] = bhhs[gjb + k];
    bz_[k] = bhhs[32 + gjb + k];
    bn_[k] = bhhs[64 + gjb + k];
  }

  const __hip_bfloat16* gibase = gi + (size_t)(rb0 + gb) * T_ * G3_ + j0 + gjb;
  // software-pipelined gi: load step-0 operands now
  u16x4 gr4 = *(const u16x4*)(gibase);
  u16x4 gz4 = *(const u16x4*)(gibase + 512);
  u16x4 gn4 = *(const u16x4*)(gibase + 1024);

  for (int t = 0; t < T_; ++t) {
    // ---- wave-autonomous wait: all 64 wave-flags at version t+1 ----
    {
      unsigned want = (unsigned)(t + 1);
      for (;;) {
        unsigned f = ld4_sys_wait(gflags + lane);
        if (__all((int)(f >= want))) break;
      }
    }

    // ---- A fragments (full h version t) direct to regs, masked ----
    const __hip_bfloat16* hsrc = hbuf + (size_t)(bg * 2 + (t & 1)) * 32 * 512;
    const char* abase = (const char*)(hsrc + (size_t)arow * 512 + asub * 8);
    bf16x8 af[16];
    #pragma unroll
    for (int kc = 0; kc < 16; ++kc) af[kc] = ld16_sys(abase + kc * 64);
    bool maskd = ((epm[t] >> arow) & 1u) != 0u;
    waitvm0();
    __builtin_amdgcn_sched_barrier(0);
    if (maskd) {
      #pragma unroll
      for (int kc = 0; kc < 16; ++kc) af[kc] = (bf16x8){0, 0, 0, 0, 0, 0, 0, 0};
    }

    // ---- gh = (mask*h) @ W^T ----
    f32x4 acc[3];
    #pragma unroll
    for (int i = 0; i < 3; ++i) acc[i] = (f32x4){0.f, 0.f, 0.f, 0.f};
    #pragma unroll
    for (int kc = 0; kc < 16; ++kc) {
      #pragma unroll
      for (int i = 0; i < 3; ++i) {
        bf16x8 bf = *(const bf16x8*)&Wl[npair * 48 + i * 16 + lr][kc * 32 + asub * 8];
        acc[i] = __builtin_amdgcn_mfma_f32_16x16x32_bf16(af[kc], bf, acc[i], 0, 0, 0);
      }
    }
    #pragma unroll
    for (int i = 0; i < 3; ++i)
      #pragma unroll
      for (int q = 0; q < 4; ++q)
        ghs[mt * 16 + asub * 4 + q][npair * 48 + i * 16 + lr] = acc[i][q];
    __syncthreads();

    // ---- gates + state update (own 32 cols, register master) ----
    __hip_bfloat16* hdst = hbuf + (size_t)(bg * 2 + ((t + 1) & 1)) * 32 * 512;
    float live = ((epm[t] >> gb) & 1u) ? 0.0f : 1.0f;
    f32x4 ghr = *(const f32x4*)&ghs[gb][gjb];
    f32x4 ghz = *(const f32x4*)&ghs[gb][32 + gjb];
    f32x4 ghn = *(const f32x4*)&ghs[gb][64 + gjb];
    f32x4 hnew;
    u16x4 hb;
    #pragma unroll
    for (int k = 0; k < 4; ++k) {
      float r = 1.0f / (1.0f + __expf(-(bu2f(gr4[k]) + ghr[k] + br_[k])));
      float z = 1.0f / (1.0f + __expf(-(bu2f(gz4[k]) + ghz[k] + bz_[k])));
      float nx = bu2f(gn4[k]) + r * (ghn[k] + bn_[k]);
      float n = 1.0f - 2.0f / (__expf(2.0f * nx) + 1.0f);   // tanh
      float hp = hreg[k] * live;
      float hv = (1.0f - z) * n + z * hp;
      hnew[k] = hv;
      hb[k] = f2bu(hv);
    }
    // critical path: publish -> drain -> per-wave flag
    st8_sys(hdst + gb * 512 + j0 + gjb, hb);
    waitvm0();
    if (lane == 0) st4_sys(gflags + nb * 4 + wave, (unsigned)(t + 2));

    // off critical path: gi prefetch (t+1), hs store, register master update
    int tn = (t + 1 < T_) ? (t + 1) : t;
    gr4 = *(const u16x4*)(gibase + (size_t)tn * G3_);
    gz4 = *(const u16x4*)(gibase + (size_t)tn * G3_ + 512);
    gn4 = *(const u16x4*)(gibase + (size_t)tn * G3_ + 1024);
    *(u16x4*)&hs[((size_t)(rb0 + gb) * T_ + t) * 512 + j0 + gjb] = hb;
    hreg = hnew;
  }

  *(float4*)(h_last + (size_t)(rb0 + gb) * 512 + j0 + gjb) =
      (float4){hreg[0], hreg[1], hreg[2], hreg[3]};
}

// ---------------- launch ----------------
extern "C" void kernel_launch(void* const* d_in, const int* in_sizes, int n_in,
                              void* d_out, int out_size, void* d_ws, size_t ws_size,
                              hipStream_t stream) {
  const float* inputs = (const float*)d_in[0];
  const float* hidden = (const float*)d_in[1];
  const int*   ep     = (const int*)d_in[2];
  const float* gamma  = (const float*)d_in[3];
  const float* beta   = (const float*)d_in[4];
  const float* w_in   = (const float*)d_in[5];
  const float* b_in   = (const float*)d_in[6];
  const float* w_ih   = (const float*)d_in[7];
  const float* b_ih   = (const float*)d_in[8];
  const float* w_hh   = (const float*)d_in[9];
  const float* b_hh   = (const float*)d_in[10];
  const float* w_out  = (const float*)d_in[11];
  const float* b_out  = (const float*)d_in[12];

  char* ws = (char*)d_ws;
  size_t off = 0;
  auto alloc = [&](size_t bytes) { char* p = ws + off; off += (bytes + 255) & ~(size_t)255; return p; };
  const size_t BT = (size_t)B_ * T_;
  __hip_bfloat16* xn   = (__hip_bfloat16*)alloc(BT * D_ * 2);      // later reused as hs
  __hip_bfloat16* x    = (__hip_bfloat16*)alloc(BT * D_ * 2);
  __hip_bfloat16* gi   = (__hip_bfloat16*)alloc(BT * G3_ * 2);
  __hip_bfloat16* wib  = (__hip_bfloat16*)alloc((size_t)D_ * D_ * 2);
  __hip_bfloat16* whb  = (__hip_bfloat16*)alloc((size_t)G3_ * D_ * 2);
  __hip_bfloat16* wob  = (__hip_bfloat16*)alloc((size_t)H_ * H_ * 2);
  __hip_bfloat16* hbuf = (__hip_bfloat16*)alloc((size_t)8 * 2 * 32 * 512 * 2);
  unsigned int*   ctrs = (unsigned int*)alloc(4096);

  float* out    = (float*)d_out;
  float* h_last = out + BT * H_;

  prep_kernel<<<3072, 256, 0, stream>>>(w_in, w_ih, w_out, wib, whb, wob, ctrs);
  ln_kernel<<<B_ * T_ / 8, 512, 0, stream>>>(inputs, gamma, beta, xn);
  gemm_bt<1, 1><<<dim3(D_ / 128, BT / 128), 256, 0, stream>>>(xn, wib, b_in, x, BT, D_, D_);
  gemm_bt<0, 1><<<dim3(G3_ / 128, BT / 128), 256, 0, stream>>>(x, whb, b_ih, gi, BT, G3_, D_);
  __hip_bfloat16* hs = xn;  // xn dead after gemm1
  scan_kernel<<<128, 256, 0, stream>>>(gi, hidden, ep, w_hh, b_hh, hs, hbuf, h_last, ctrs);
  gemm_bt<1, 0><<<dim3(H_ / 128, BT / 128), 256, 0, stream>>>(hs, wob, b_out, d_out, BT, H_, H_);
}

// Round 4
// 1798.607 us; speedup vs baseline: 1.3392x; 1.3392x over previous
//
#include <hip/hip_runtime.h>
#include <hip/hip_bf16.h>

#define B_  256
#define T_  256
#define D_  512
#define H_  512
#define G3_ 1536

typedef __attribute__((ext_vector_type(8))) short bf16x8;
typedef __attribute__((ext_vector_type(4))) float f32x4;
typedef __attribute__((ext_vector_type(8))) unsigned short u16x8;
typedef __attribute__((ext_vector_type(4))) unsigned short u16x4;

__device__ inline void gload_lds16(const void* g, void* l) {
  __builtin_amdgcn_global_load_lds((const __attribute__((address_space(1))) void*)g,
                                   (__attribute__((address_space(3))) void*)l,
                                   16, 0, 0);
}

__device__ inline unsigned short f2bu(float f) {
  __hip_bfloat16 h = __float2bfloat16(f);
  return *reinterpret_cast<unsigned short*>(&h);
}
__device__ inline float bu2f(unsigned short u) {
  return __uint_as_float((unsigned)u << 16);
}

// ---- system-coherent (MALL) access helpers: bypass L1/L2 so cross-block
// ---- exchange needs NO cache-maintenance ops per step.
__device__ inline bf16x8 ld16_sys(const void* p) {
  bf16x8 r;
  asm volatile("global_load_dwordx4 %0, %1, off sc0 sc1" : "=v"(r) : "v"(p) : "memory");
  return r;
}
__device__ inline void st8_sys(void* p, u16x4 v) {
  asm volatile("global_store_dwordx2 %0, %1, off sc0 sc1" :: "v"(p), "v"(v) : "memory");
}
__device__ inline void st4_sys(void* p, unsigned v) {
  asm volatile("global_store_dword %0, %1, off sc0 sc1" :: "v"(p), "v"(v) : "memory");
}
__device__ inline unsigned ld4_sys_wait(const void* p) {
  unsigned r;
  asm volatile("global_load_dword %0, %1, off sc0 sc1\n\ts_waitcnt vmcnt(0)"
               : "=v"(r) : "v"(p) : "memory");
  return r;
}
__device__ inline void waitvm0() { asm volatile("s_waitcnt vmcnt(0)" ::: "memory"); }

// ---------------- prep: weights f32->bf16, zero flags ----------------
__global__ void prep_kernel(const float* __restrict__ w_in, const float* __restrict__ w_ih,
                            const float* __restrict__ w_out,
                            __hip_bfloat16* __restrict__ wib, __hip_bfloat16* __restrict__ whb,
                            __hip_bfloat16* __restrict__ wob, unsigned int* __restrict__ ctrs) {
  int i = blockIdx.x * 256 + threadIdx.x;
  if (i < D_ * D_)  wib[i] = __float2bfloat16(w_in[i]);
  if (i < G3_ * D_) whb[i] = __float2bfloat16(w_ih[i]);
  if (i < H_ * H_)  wob[i] = __float2bfloat16(w_out[i]);
  if (i < 1024) ctrs[i] = 0u;
}

// ---------------- LayerNorm + cast to bf16 (1 wave per 512-col row) ----------------
__global__ __launch_bounds__(512) void ln_kernel(const float* __restrict__ x,
                                                 const float* __restrict__ gamma,
                                                 const float* __restrict__ beta,
                                                 __hip_bfloat16* __restrict__ xn) {
  long row = (long)blockIdx.x * 8 + (threadIdx.x >> 6);
  int lane = threadIdx.x & 63;
  const float4* rp = (const float4*)(x + row * D_ + lane * 8);
  float4 v0 = rp[0], v1 = rp[1];
  float s  = v0.x + v0.y + v0.z + v0.w + v1.x + v1.y + v1.z + v1.w;
  float sq = v0.x*v0.x + v0.y*v0.y + v0.z*v0.z + v0.w*v0.w
           + v1.x*v1.x + v1.y*v1.y + v1.z*v1.z + v1.w*v1.w;
  #pragma unroll
  for (int off = 1; off < 64; off <<= 1) { s += __shfl_xor(s, off); sq += __shfl_xor(sq, off); }
  float mean = s * (1.0f / D_);
  float var  = sq * (1.0f / D_) - mean * mean;
  float rstd = rsqrtf(var + 1e-5f);
  const float4* gp = (const float4*)(gamma + lane * 8);
  const float4* bp = (const float4*)(beta + lane * 8);
  float4 g0 = gp[0], g1 = gp[1], bb0 = bp[0], bb1 = bp[1];
  float vv[8] = {v0.x, v0.y, v0.z, v0.w, v1.x, v1.y, v1.z, v1.w};
  float gg[8] = {g0.x, g0.y, g0.z, g0.w, g1.x, g1.y, g1.z, g1.w};
  float bt[8] = {bb0.x, bb0.y, bb0.z, bb0.w, bb1.x, bb1.y, bb1.z, bb1.w};
  u16x8 ov;
  #pragma unroll
  for (int i = 0; i < 8; ++i) ov[i] = f2bu((vv[i] - mean) * rstd * gg[i] + bt[i]);
  *(u16x8*)(xn + row * D_ + lane * 8) = ov;
}

// ---------------- GEMM: C[M,N] = act(A[M,K] @ W[N,K]^T + bias) ----------------
template<int ACT, int OUTBF>
__global__ __launch_bounds__(256) void gemm_bt(const __hip_bfloat16* __restrict__ A,
                                               const __hip_bfloat16* __restrict__ W,
                                               const float* __restrict__ bias,
                                               void* __restrict__ Cout,
                                               int M, int N, int K) {
  __shared__ __hip_bfloat16 As[128 * 64];
  __shared__ __hip_bfloat16 Ws[128 * 64];
  int tid  = threadIdx.x;
  int lane = tid & 63;
  int wave = tid >> 6;
  long row0 = (long)blockIdx.y * 128;
  long col0 = (long)blockIdx.x * 128;
  int qm = (wave >> 1) * 64, qn = (wave & 1) * 64;
  int lr = lane & 15, lk = (lane >> 4) * 8;
  f32x4 acc[4][4];
  #pragma unroll
  for (int mt = 0; mt < 4; ++mt)
    #pragma unroll
    for (int nt = 0; nt < 4; ++nt) acc[mt][nt] = {0.f, 0.f, 0.f, 0.f};

  for (int k0 = 0; k0 < K; k0 += 64) {
    #pragma unroll
    for (int i = 0; i < 4; ++i) {
      int e = i * 2048 + tid * 8;
      int r = e >> 6, c = e & 63;
      gload_lds16(A + (row0 + r) * K + k0 + c, (char*)As + 2 * e);
      gload_lds16(W + (col0 + r) * K + k0 + c, (char*)Ws + 2 * e);
    }
    __syncthreads();
    #pragma unroll
    for (int kc = 0; kc < 2; ++kc) {
      int kb = kc * 32 + lk;
      bf16x8 af[4], wf[4];
      #pragma unroll
      for (int mt = 0; mt < 4; ++mt) af[mt] = *(const bf16x8*)&As[(qm + mt * 16 + lr) * 64 + kb];
      #pragma unroll
      for (int nt = 0; nt < 4; ++nt) wf[nt] = *(const bf16x8*)&Ws[(qn + nt * 16 + lr) * 64 + kb];
      #pragma unroll
      for (int mt = 0; mt < 4; ++mt)
        #pragma unroll
        for (int nt = 0; nt < 4; ++nt)
          acc[mt][nt] = __builtin_amdgcn_mfma_f32_16x16x32_bf16(af[mt], wf[nt], acc[mt][nt], 0, 0, 0);
    }
    __syncthreads();
  }
  int r0 = (lane >> 4) * 4;
  #pragma unroll
  for (int nt = 0; nt < 4; ++nt) {
    long col = col0 + qn + nt * 16 + lr;
    float bv = bias[col];
    #pragma unroll
    for (int mt = 0; mt < 4; ++mt) {
      #pragma unroll
      for (int q = 0; q < 4; ++q) {
        long row = row0 + qm + mt * 16 + r0 + q;
        float v = acc[mt][nt][q] + bv;
        if (ACT) v = fmaxf(v, 0.0f);
        if (OUTBF) ((__hip_bfloat16*)Cout)[row * N + col] = __float2bfloat16(v);
        else       ((float*)Cout)[row * N + col] = v;
      }
    }
  }
}

// ---------------- GRU scan ----------------
// 8 groups (32 batch rows) x 16 blocks (32 h-cols -> 96 w_hh rows LDS-resident).
// R2 protocol (measured best): one flag per block, published by tid0 after a
// block-wide publish drain; wave0-only poll of 16 flags with s_sleep backoff.
// R3's off-critical-path improvements kept: hs store + gi prefetch after the
// flag publish; register-resident h master; biases in registers.
__global__ __launch_bounds__(256) void scan_kernel(const __hip_bfloat16* __restrict__ gi,
                                                   const float* __restrict__ hidden,
                                                   const int* __restrict__ ep,
                                                   const float* __restrict__ w_hh,
                                                   const float* __restrict__ b_hh,
                                                   __hip_bfloat16* __restrict__ hs,
                                                   __hip_bfloat16* __restrict__ hbuf,
                                                   float* __restrict__ h_last,
                                                   unsigned int* __restrict__ flags) {
  __shared__ __hip_bfloat16 Wl[96][520];   // gate rows: [0,32)=r [32,64)=z [64,96)=n
  __shared__ float ghs[32][100];
  __shared__ unsigned epm[256];            // per-t bitmask of episode starts (32 rows)
  __shared__ float bhhs[96];

  const int tid = threadIdx.x;
  const int bg = blockIdx.x & 7;           // group ~ XCD (heuristic only)
  const int nb = blockIdx.x >> 3;          // 0..15
  const int rb0 = bg * 32;
  const int j0 = nb * 32;
  unsigned* gflags = flags + bg * 16;      // one flag per block

  // W slice f32->bf16 -> LDS (resident all T steps)
  for (int idx = tid; idx < 96 * 512; idx += 256) {
    int row = idx >> 9, c = idx & 511;
    int g = row >> 5, jj = row & 31;
    Wl[row][c] = __float2bfloat16(w_hh[(size_t)(g * 512 + j0 + jj) * 512 + c]);
  }
  if (tid < 96) bhhs[tid] = b_hh[(tid >> 5) * 512 + j0 + (tid & 31)];
  {
    unsigned m = 0;
    for (int b = 0; b < 32; ++b)
      m |= (ep[(rb0 + b) * T_ + tid] != 0) ? (1u << b) : 0u;
    epm[tid] = m;
  }

  const int lane = tid & 63;
  const int wave = tid >> 6;
  const int gb = tid >> 3, gjb = (tid & 7) * 4;   // gate-phase cell (row, 4-col chunk)

  // init h: register master + publish bf16 (buffer 0)
  f32x4 hreg;
  {
    const float4 hv = *(const float4*)(hidden + (size_t)(rb0 + gb) * 512 + j0 + gjb);
    hreg = (f32x4){hv.x, hv.y, hv.z, hv.w};
    u16x4 hb;
    #pragma unroll
    for (int k = 0; k < 4; ++k) hb[k] = f2bu(hreg[k]);
    st8_sys(hbuf + (size_t)(bg * 2) * 32 * 512 + gb * 512 + j0 + gjb, hb);
  }
  waitvm0();
  __syncthreads();                          // publishes drained + Wl/epm/bhhs ready
  if (tid == 0) st4_sys(gflags + nb, 1u);

  const int mt = wave >> 1;                // batch half (rows 0-15 / 16-31)
  const int npair = wave & 1;              // gate half (rows 0-47 / 48-95)
  const int lr = lane & 15;
  const int asub = lane >> 4;
  const int arow = mt * 16 + lr;           // batch row in group

  // loop-invariant gate biases -> registers
  float br_[4], bz_[4], bn_[4];
  #pragma unroll
  for (int k = 0; k < 4; ++k) {
    br_[k] = bhhs[gjb + k];
    bz_[k] = bhhs[32 + gjb + k];
    bn_[k] = bhhs[64 + gjb + k];
  }

  const __hip_bfloat16* gibase = gi + (size_t)(rb0 + gb) * T_ * G3_ + j0 + gjb;
  // software-pipelined gi: load step-0 operands now
  u16x4 gr4 = *(const u16x4*)(gibase);
  u16x4 gz4 = *(const u16x4*)(gibase + 512);
  u16x4 gn4 = *(const u16x4*)(gibase + 1024);

  for (int t = 0; t < T_; ++t) {
    // ---- wait: all 16 blocks published version t (wave0 polls, with backoff) ----
    if (wave == 0) {
      unsigned want = (unsigned)(t + 1);
      for (;;) {
        unsigned f = ld4_sys_wait(gflags + (lane & 15));
        if (__all((int)(f >= want))) break;
        __builtin_amdgcn_s_sleep(1);
      }
    }
    __syncthreads();

    // ---- A fragments (full h version t) direct to regs, masked ----
    const __hip_bfloat16* hsrc = hbuf + (size_t)(bg * 2 + (t & 1)) * 32 * 512;
    const char* abase = (const char*)(hsrc + (size_t)arow * 512 + asub * 8);
    bf16x8 af[16];
    #pragma unroll
    for (int kc = 0; kc < 16; ++kc) af[kc] = ld16_sys(abase + kc * 64);
    bool maskd = ((epm[t] >> arow) & 1u) != 0u;
    waitvm0();
    __builtin_amdgcn_sched_barrier(0);
    if (maskd) {
      #pragma unroll
      for (int kc = 0; kc < 16; ++kc) af[kc] = (bf16x8){0, 0, 0, 0, 0, 0, 0, 0};
    }

    // ---- gh = (mask*h) @ W^T ----
    f32x4 acc[3];
    #pragma unroll
    for (int i = 0; i < 3; ++i) acc[i] = (f32x4){0.f, 0.f, 0.f, 0.f};
    #pragma unroll
    for (int kc = 0; kc < 16; ++kc) {
      #pragma unroll
      for (int i = 0; i < 3; ++i) {
        bf16x8 bf = *(const bf16x8*)&Wl[npair * 48 + i * 16 + lr][kc * 32 + asub * 8];
        acc[i] = __builtin_amdgcn_mfma_f32_16x16x32_bf16(af[kc], bf, acc[i], 0, 0, 0);
      }
    }
    #pragma unroll
    for (int i = 0; i < 3; ++i)
      #pragma unroll
      for (int q = 0; q < 4; ++q)
        ghs[mt * 16 + asub * 4 + q][npair * 48 + i * 16 + lr] = acc[i][q];
    __syncthreads();

    // ---- gates + state update (own 32 cols, register master) ----
    __hip_bfloat16* hdst = hbuf + (size_t)(bg * 2 + ((t + 1) & 1)) * 32 * 512;
    float live = ((epm[t] >> gb) & 1u) ? 0.0f : 1.0f;
    f32x4 ghr = *(const f32x4*)&ghs[gb][gjb];
    f32x4 ghz = *(const f32x4*)&ghs[gb][32 + gjb];
    f32x4 ghn = *(const f32x4*)&ghs[gb][64 + gjb];
    f32x4 hnew;
    u16x4 hb;
    #pragma unroll
    for (int k = 0; k < 4; ++k) {
      float r = 1.0f / (1.0f + __expf(-(bu2f(gr4[k]) + ghr[k] + br_[k])));
      float z = 1.0f / (1.0f + __expf(-(bu2f(gz4[k]) + ghz[k] + bz_[k])));
      float nx = bu2f(gn4[k]) + r * (ghn[k] + bn_[k]);
      float n = 1.0f - 2.0f / (__expf(2.0f * nx) + 1.0f);   // tanh
      float hp = hreg[k] * live;
      float hv = (1.0f - z) * n + z * hp;
      hnew[k] = hv;
      hb[k] = f2bu(hv);
    }
    // critical path: publish -> per-wave drain -> block barrier -> tid0 flag
    st8_sys(hdst + gb * 512 + j0 + gjb, hb);
    waitvm0();
    __syncthreads();
    if (tid == 0) st4_sys(gflags + nb, (unsigned)(t + 2));

    // off critical path: gi prefetch (t+1), hs store, register master update
    int tn = (t + 1 < T_) ? (t + 1) : t;
    gr4 = *(const u16x4*)(gibase + (size_t)tn * G3_);
    gz4 = *(const u16x4*)(gibase + (size_t)tn * G3_ + 512);
    gn4 = *(const u16x4*)(gibase + (size_t)tn * G3_ + 1024);
    *(u16x4*)&hs[((size_t)(rb0 + gb) * T_ + t) * 512 + j0 + gjb] = hb;
    hreg = hnew;
  }

  *(float4*)(h_last + (size_t)(rb0 + gb) * 512 + j0 + gjb) =
      (float4){hreg[0], hreg[1], hreg[2], hreg[3]};
}

// ---------------- launch ----------------
extern "C" void kernel_launch(void* const* d_in, const int* in_sizes, int n_in,
                              void* d_out, int out_size, void* d_ws, size_t ws_size,
                              hipStream_t stream) {
  const float* inputs = (const float*)d_in[0];
  const float* hidden = (const float*)d_in[1];
  const int*   ep     = (const int*)d_in[2];
  const float* gamma  = (const float*)d_in[3];
  const float* beta   = (const float*)d_in[4];
  const float* w_in   = (const float*)d_in[5];
  const float* b_in   = (const float*)d_in[6];
  const float* w_ih   = (const float*)d_in[7];
  const float* b_ih   = (const float*)d_in[8];
  const float* w_hh   = (const float*)d_in[9];
  const float* b_hh   = (const float*)d_in[10];
  const float* w_out  = (const float*)d_in[11];
  const float* b_out  = (const float*)d_in[12];

  char* ws = (char*)d_ws;
  size_t off = 0;
  auto alloc = [&](size_t bytes) { char* p = ws + off; off += (bytes + 255) & ~(size_t)255; return p; };
  const size_t BT = (size_t)B_ * T_;
  __hip_bfloat16* xn   = (__hip_bfloat16*)alloc(BT * D_ * 2);      // later reused as hs
  __hip_bfloat16* x    = (__hip_bfloat16*)alloc(BT * D_ * 2);
  __hip_bfloat16* gi   = (__hip_bfloat16*)alloc(BT * G3_ * 2);
  __hip_bfloat16* wib  = (__hip_bfloat16*)alloc((size_t)D_ * D_ * 2);
  __hip_bfloat16* whb  = (__hip_bfloat16*)alloc((size_t)G3_ * D_ * 2);
  __hip_bfloat16* wob  = (__hip_bfloat16*)alloc((size_t)H_ * H_ * 2);
  __hip_bfloat16* hbuf = (__hip_bfloat16*)alloc((size_t)8 * 2 * 32 * 512 * 2);
  unsigned int*   ctrs = (unsigned int*)alloc(4096);

  float* out    = (float*)d_out;
  float* h_last = out + BT * H_;

  prep_kernel<<<3072, 256, 0, stream>>>(w_in, w_ih, w_out, wib, whb, wob, ctrs);
  ln_kernel<<<B_ * T_ / 8, 512, 0, stream>>>(inputs, gamma, beta, xn);
  gemm_bt<1, 1><<<dim3(D_ / 128, BT / 128), 256, 0, stream>>>(xn, wib, b_in, x, BT, D_, D_);
  gemm_bt<0, 1><<<dim3(G3_ / 128, BT / 128), 256, 0, stream>>>(x, whb, b_ih, gi, BT, G3_, D_);
  __hip_bfloat16* hs = xn;  // xn dead after gemm1
  scan_kernel<<<128, 256, 0, stream>>>(gi, hidden, ep, w_hh, b_hh, hs, hbuf, h_last, ctrs);
  gemm_bt<1, 0><<<dim3(H_ / 128, BT / 128), 256, 0, stream>>>(hs, wob, b_out, d_out, BT, H_, H_);
}